// Round 9
// baseline (537.165 us; speedup 1.0000x reference)
//
#include <hip/hip_runtime.h>

// PairwiseMLPLinkPredictor on MI355X (gfx950)
// feats = bf16(x[u]) * bf16(x[v]);  h1 = relu(feats@W1+b1);  h2 = relu(h1@W2+b2);
// out = h2@W3 + b3.
//
// R13: R6 role-split dataflow x (1024,1) launch bounds.
// Five-point occupancy model (R5-R12): budget = 512/clamp(minblk*wavesperblk/4,1,8)
//   (1024,4)->64, (512,2)->128, (512,4)->64, waves_per_eu ignored,
//   and 2-block exact-full-file (2x8x128=2048) does NOT co-schedule (R12: 22.8%).
// (1024,1): 16-wave single block, budget 128 -- compiler MUST fit (launch promise),
// giving 128-reg budget AND 16 waves/CU at once. The R6 role-split needed exactly
// this: per-role weights 64 regs + acc 16 + staging 16 ~ 110 < 128.
//  - 8 P-waves: GEMM1 64r x 32c -> packed-b32 h1 writeback (R8-verified + k-perm w2t)
//  - 8 C-waves: GEMM2 32r x 32c -> layer-3 partials -> part[]
//  - double-buffered feats/h1/part: ONE barrier/tile (R6-verified schedule)
//  - deferred out-store (tile i-2) by P wave 0; epilogue for last tile
//  - LDS 130KB, 1 block/CU; heterogeneous P/C overlap replaces block-level TLP

typedef __attribute__((ext_vector_type(8))) short short8;   // 8 bf16 = 4 VGPRs
typedef __attribute__((ext_vector_type(4))) float floatx4;  // MFMA C/D frag
typedef __attribute__((ext_vector_type(4))) unsigned uintx4;
typedef __attribute__((ext_vector_type(2))) int intx2;

#define MT 64          // pairs per tile
#define NTHREADS 1024  // 16 waves: 8 producer + 8 consumer
#define NBLOCKS 256    // persistent, 1 block/CU

__device__ __forceinline__ unsigned short f2bf(float f) {
  union { float f; unsigned u; } a; a.f = f;
  unsigned r = a.u + 0x7FFFu + ((a.u >> 16) & 1u);   // RNE
  return (unsigned short)(r >> 16);
}

// hw packed f32x2 -> bf16x2 (RNE), lo in low 16
__device__ __forceinline__ unsigned pkbf(float lo, float hi) {
  unsigned r;
  asm("v_cvt_pk_bf16_f32 %0, %1, %2" : "=v"(r) : "v"(lo), "v"(hi));
  return r;
}

// packed bf16x2 multiply via f32 unpack + hw repack
__device__ __forceinline__ unsigned bfmul2(unsigned ua, unsigned ub) {
  float lo = __uint_as_float(ua << 16)          * __uint_as_float(ub << 16);
  float hi = __uint_as_float(ua & 0xFFFF0000u) * __uint_as_float(ub & 0xFFFF0000u);
  return pkbf(lo, hi);
}

// ---------- prologue: x -> bf16 table; W1/W2 -> bf16 transposed [n][k] ----------
// w2t's k-dimension is stored PERMUTED: storage index p holds logical k
// kperm(p) = (p & ~31) | ((p&1)<<4) | ((p&31)>>1), matching the packed h1
// writeback (lane packs cols n1, n1+16 into adjacent storage slots 2*r16, 2*r16+1).
__global__ void prep_kernel(const float* __restrict__ x,
                            const float* __restrict__ W1,
                            const float* __restrict__ W2,
                            unsigned short* __restrict__ xb,
                            unsigned short* __restrict__ w1t,
                            unsigned short* __restrict__ w2t, int n4) {
  int i = blockIdx.x * blockDim.x + threadIdx.x;
  if (i < n4) {
    float4 v = ((const float4*)x)[i];
    ushort4 o;
    o.x = f2bf(v.x); o.y = f2bf(v.y); o.z = f2bf(v.z); o.w = f2bf(v.w);
    ((ushort4*)xb)[i] = o;
  } else {
    int j = i - n4;
    if (j < 256 * 256) {
      int k = j >> 8, n = j & 255;
      w1t[n * 256 + k] = f2bf(W1[k * 256 + n]);
    } else {
      j -= 256 * 256;
      if (j < 128 * 256) {
        int p = j >> 7, n = j & 127;                       // p = storage k-index
        int kp = (p & ~31) | ((p & 1) << 4) | ((p & 31) >> 1);
        w2t[n * 256 + p] = f2bf(W2[kp * 128 + n]);
      }
    }
  }
}

// ---------- fused pairwise MLP, persistent, role-split P/C, 1 barrier/tile ----------
__global__ __launch_bounds__(NTHREADS, 1) void mlp_kernel(
    const unsigned short* __restrict__ xb,
    const unsigned short* __restrict__ w1t,
    const unsigned short* __restrict__ w2t,
    const float* __restrict__ b1,
    const float* __restrict__ b2,
    const float* __restrict__ w3,
    const float* __restrict__ b3,
    const int* __restrict__ ep,
    float* __restrict__ out,
    int E)
{
  // 16B chunks XOR-swizzled by (row & 15): conflict-free stride-512 ds_read_b128.
  __shared__ __align__(16) unsigned short feats[2][MT * 256]; // 64 KB
  __shared__ __align__(16) unsigned short h1b[2][MT * 256];   // 64 KB
  __shared__ __align__(16) float part[2][MT][4];              // 2 KB

  const int tid  = threadIdx.x;
  const int wv   = tid >> 6;      // 0..15
  const int lane = tid & 63;
  const int q    = lane >> 4;     // quad 0..3
  const int r16  = lane & 15;
  const int c    = tid & 31;      // 16B chunk within 512B row (staging)
  const int mr0  = tid >> 5;      // staging row base 0..31 (rows mr0, mr0+32)
  const bool isP = (wv < 8);
  const int cw   = wv & 7;        // consumer wave index 0..7
  const int mg2  = cw >> 2;       // GEMM2 row slab 0..1
  const int cg2  = cw & 3;        // GEMM2 col group 0..3

  const int ntiles = (E + MT - 1) / MT;        // 15625 (E = 64*15625 exactly)
  const int b = blockIdx.x;
  const int nloc = (ntiles - 1 - b) / NBLOCKS + 1;   // ~61-62 tiles/block

  // ---- per-role weights: ONE 2ct x 8kt array = 64 VGPR ----
  short8 wA[2][8];
  float bA[2], wS[2];
  if (isP) {
    #pragma unroll
    for (int ct = 0; ct < 2; ++ct) {
      const int n = wv * 32 + ct * 16 + r16;           // W1 col 0..255
      const unsigned short* p = w1t + n * 256 + q * 8;
      #pragma unroll
      for (int kt = 0; kt < 8; ++kt) wA[ct][kt] = *(const short8*)(p + kt * 32);
      bA[ct] = b1[n];
      wS[ct] = 0.f;
    }
  } else {
    #pragma unroll
    for (int ct = 0; ct < 2; ++ct) {
      const int n = cg2 * 32 + ct * 16 + r16;          // W2 col 0..127
      const unsigned short* p = w2t + n * 256 + q * 8; // (k-permuted storage)
      #pragma unroll
      for (int kt = 0; kt < 8; ++kt) wA[ct][kt] = *(const short8*)(p + kt * 32);
      bA[ct] = b2[n];
      wS[ct] = w3[n];
    }
  }
  const float b3v = b3[0];

  // ---- prologue: stage tile b into feats[0]; load uv for tile b+NBLOCKS ----
  intx2 uvA, uvB;
  {
    #pragma unroll
    for (int s = 0; s < 2; ++s) {
      int m = mr0 + 32 * s;
      int g = b * MT + m;                      // < 256*64 << E, no clamp needed
      intx2 uv = __builtin_nontemporal_load((const intx2*)(ep + 2 * (size_t)g));
      uintx4 a  = *(const uintx4*)(xb + ((size_t)(unsigned)uv.x << 8) + (c << 3));
      uintx4 bv = *(const uintx4*)(xb + ((size_t)(unsigned)uv.y << 8) + (c << 3));
      uintx4 pv;
      #pragma unroll
      for (int tt = 0; tt < 4; ++tt) pv[tt] = bfmul2(a[tt], bv[tt]);
      *(uintx4*)((char*)feats[0] + m * 512 + ((c ^ (m & 15)) << 4)) = pv;
    }
    const int t1 = b + NBLOCKS;                // < 512 < ntiles, no clamp
    uvA = __builtin_nontemporal_load((const intx2*)(ep + 2 * (size_t)(t1 * MT + mr0)));
    uvB = __builtin_nontemporal_load((const intx2*)(ep + 2 * (size_t)(t1 * MT + mr0 + 32)));
  }
  __syncthreads();

  // iter i: P: GEMM1(tile i)->h1b[fp], store(tile i-2);  C: GEMM2(tile i-1)->part[fp]
  //         all: stage feats(i+1)->feats[fp^1];  ONE barrier.
  for (int i = 0; i <= nloc; ++i) {
    const int fp = i & 1;
    const bool stg = (i + 1 < nloc);

    // ---- (1) issue next-tile gather loads (latency covered by GEMM phase) ----
    uintx4 ra0, rb0, ra1, rb1;
    if (stg) {
      ra0 = *(const uintx4*)(xb + ((size_t)(unsigned)uvA.x << 8) + (c << 3));
      rb0 = *(const uintx4*)(xb + ((size_t)(unsigned)uvA.y << 8) + (c << 3));
      ra1 = *(const uintx4*)(xb + ((size_t)(unsigned)uvB.x << 8) + (c << 3));
      rb1 = *(const uintx4*)(xb + ((size_t)(unsigned)uvB.y << 8) + (c << 3));
    }

    if (isP) {
      // ============ producer: GEMM1 tile i (two 32-row halves) ============
      if (i < nloc) {
        char* const hb  = (char*)h1b[fp];
        const int chp = wv * 4 + (r16 >> 2);
        const int ino = (r16 & 3) << 2;
        #pragma unroll
        for (int mh = 0; mh < 2; ++mh) {
          floatx4 acc[2][2];
          #pragma unroll
          for (int mt = 0; mt < 2; ++mt) {
            acc[mt][0] = (floatx4){0.f, 0.f, 0.f, 0.f};
            acc[mt][1] = (floatx4){0.f, 0.f, 0.f, 0.f};
          }
          const char* const a1base =
              (const char*)feats[fp] + r16 * 512 + mh * (32 * 512);
          #pragma unroll
          for (int kt = 0; kt < 8; ++kt) {
            const int aoff = (kt << 6) ^ ((q ^ r16) << 4);
            #pragma unroll
            for (int mt = 0; mt < 2; ++mt) {
              short8 av = *(const short8*)(a1base + mt * (16 * 512) + aoff);
              acc[mt][0] = __builtin_amdgcn_mfma_f32_16x16x32_bf16(av, wA[0][kt], acc[mt][0], 0, 0, 0);
              acc[mt][1] = __builtin_amdgcn_mfma_f32_16x16x32_bf16(av, wA[1][kt], acc[mt][1], 0, 0, 0);
            }
          }
          // packed h1 writeback: (ct0,ct1) -> one b32 store per (mt,r)
          #pragma unroll
          for (int mt = 0; mt < 2; ++mt) {
            #pragma unroll
            for (int r = 0; r < 4; ++r) {
              const int m = mh * 32 + mt * 16 + q * 4 + r;
              unsigned pk = pkbf(fmaxf(acc[mt][0][r] + bA[0], 0.f),
                                 fmaxf(acc[mt][1][r] + bA[1], 0.f));
              *(unsigned*)(hb + m * 512 + ((chp ^ (m & 15)) << 4) + ino) = pk;
            }
          }
        }
      }
      // deferred output store: part[fp^1] holds tile i-2 (written at iter i-1)
      if (i >= 2 && tid < MT) {
        floatx4 pr = *(const floatx4*)part[fp ^ 1][tid];
        out[(size_t)(b + (i - 2) * NBLOCKS) * MT + tid] =
            (pr[0] + pr[1]) + (pr[2] + pr[3]) + b3v;
      }
    } else {
      // ============ consumer: GEMM2 tile i-1 ============
      if (i >= 1) {
        floatx4 acc2[2][2];
        acc2[0][0] = (floatx4){0.f, 0.f, 0.f, 0.f};
        acc2[0][1] = (floatx4){0.f, 0.f, 0.f, 0.f};
        acc2[1][0] = (floatx4){0.f, 0.f, 0.f, 0.f};
        acc2[1][1] = (floatx4){0.f, 0.f, 0.f, 0.f};
        const char* const a2base =
            (const char*)h1b[fp ^ 1] + (mg2 * 32 + r16) * 512;
        #pragma unroll
        for (int kt = 0; kt < 8; ++kt) {
          const int aoff = (kt << 6) ^ ((q ^ r16) << 4);
          short8 av0 = *(const short8*)(a2base + aoff);
          short8 av1 = *(const short8*)(a2base + 16 * 512 + aoff);
          acc2[0][0] = __builtin_amdgcn_mfma_f32_16x16x32_bf16(av0, wA[0][kt], acc2[0][0], 0, 0, 0);
          acc2[0][1] = __builtin_amdgcn_mfma_f32_16x16x32_bf16(av0, wA[1][kt], acc2[0][1], 0, 0, 0);
          acc2[1][0] = __builtin_amdgcn_mfma_f32_16x16x32_bf16(av1, wA[0][kt], acc2[1][0], 0, 0, 0);
          acc2[1][1] = __builtin_amdgcn_mfma_f32_16x16x32_bf16(av1, wA[1][kt], acc2[1][1], 0, 0, 0);
        }
        // layer 3 partials -> part[fp]
        #pragma unroll
        for (int mt = 0; mt < 2; ++mt) {
          #pragma unroll
          for (int r = 0; r < 4; ++r) {
            float pp = fmaxf(acc2[mt][0][r] + bA[0], 0.f) * wS[0]
                     + fmaxf(acc2[mt][1][r] + bA[1], 0.f) * wS[1];
            pp += __shfl_xor(pp, 1);
            pp += __shfl_xor(pp, 2);
            pp += __shfl_xor(pp, 4);
            pp += __shfl_xor(pp, 8);
            if (r16 == 0)
              part[fp][mg2 * 32 + mt * 16 + q * 4 + r][cg2] = pp;
          }
        }
      }
    }

    // ---- consume gathers -> feats[fp^1]; prefetch uv for tile i+2 ----
    if (stg) {
      char* const bufn = (char*)feats[fp ^ 1];
      uintx4 pv0, pv1;
      #pragma unroll
      for (int tt = 0; tt < 4; ++tt) pv0[tt] = bfmul2(ra0[tt], rb0[tt]);
      #pragma unroll
      for (int tt = 0; tt < 4; ++tt) pv1[tt] = bfmul2(ra1[tt], rb1[tt]);
      const int m0 = mr0, m1 = mr0 + 32;
      *(uintx4*)(bufn + m0 * 512 + ((c ^ (m0 & 15)) << 4)) = pv0;
      *(uintx4*)(bufn + m1 * 512 + ((c ^ (m1 & 15)) << 4)) = pv1;

      const int t2 = b + (i + 2) * NBLOCKS;
      int g0 = t2 * MT + mr0;      if (g0 >= E) g0 = E - 1;
      int g1 = t2 * MT + mr0 + 32; if (g1 >= E) g1 = E - 1;
      uvA = __builtin_nontemporal_load((const intx2*)(ep + 2 * (size_t)g0));
      uvB = __builtin_nontemporal_load((const intx2*)(ep + 2 * (size_t)g1));
    }
    __syncthreads();   // the ONLY barrier: flips all double-buffers
  }

  // epilogue: tile nloc-1's partials were written at i=nloc into part[nloc&1]
  if (tid < MT) {
    floatx4 pr = *(const floatx4*)part[nloc & 1][tid];
    out[(size_t)(b + (nloc - 1) * NBLOCKS) * MT + tid] =
        (pr[0] + pr[1]) + (pr[2] + pr[3]) + b3v;
  }
}

extern "C" void kernel_launch(void* const* d_in, const int* in_sizes, int n_in,
                              void* d_out, int out_size, void* d_ws, size_t ws_size,
                              hipStream_t stream) {
  const float* x  = (const float*)d_in[0];
  const float* W1 = (const float*)d_in[1];
  const float* b1 = (const float*)d_in[2];
  const float* W2 = (const float*)d_in[3];
  const float* b2 = (const float*)d_in[4];
  const float* W3 = (const float*)d_in[5];
  const float* b3 = (const float*)d_in[6];
  // d_in[7] = edge_index (unused by the reference computation)
  const int*   ep = (const int*)d_in[8];
  float* out = (float*)d_out;

  const int NX = in_sizes[0];        // 100000*256 = 25,600,000
  const int E  = in_sizes[8] / 2;    // 1,000,000

  // workspace layout: xb (NX bf16) | w1t (256*256 bf16) | w2t (128*256 bf16)
  unsigned short* xb  = (unsigned short*)d_ws;
  unsigned short* w1t = (unsigned short*)((char*)d_ws + (size_t)NX * 2);
  unsigned short* w2t = w1t + 256 * 256;

  const int n4 = NX / 4;
  const int prep_threads = n4 + 256 * 256 + 128 * 256;
  prep_kernel<<<(prep_threads + 255) / 256, 256, 0, stream>>>(x, W1, W2, xb, w1t, w2t, n4);
  mlp_kernel<<<NBLOCKS, NTHREADS, 0, stream>>>(xb, w1t, w2t, b1, b2, W3, b3, ep, out, E);
}